// Round 10
// baseline (410.759 us; speedup 1.0000x reference)
//
#include <hip/hip_runtime.h>
#include <stdint.h>

typedef unsigned int uint;
typedef unsigned short ushort;

#define NNODES 100000
#define NPAD   100096          // NNODES rounded up to 128
#define NEDGES 1600000
#define RCONST 400
#define CAP    64              // fixed per-node edge capacity
#define ZROW   NNODES          // guaranteed-zero row in xb0/xb1, used for segment padding

// atomic-free binned CSR build
#define NBKT   196             // ceil(NPAD / 512)
#define NBLK_A 512             // binfill blocks
#define EPB    3125            // NEDGES / NBLK_A, exact
#define RUNCAP 64              // per-(block,bucket) slot capacity; mean 16, P(>64)~2e-18
#define NCONVX 25024           // NPAD*64/256

typedef __attribute__((ext_vector_type(8))) short short8;
typedef __attribute__((ext_vector_type(4))) float f32x4;

__device__ __forceinline__ float bflo(uint u){ union{uint i;float f;}c; c.i=u<<16; return c.f; }
__device__ __forceinline__ float bfhi(uint u){ union{uint i;float f;}c; c.i=u&0xFFFF0000u; return c.f; }
__device__ __forceinline__ ushort f2bf(float f){ union{uint i;float ff;}c; c.ff=f; uint u=c.i;
    return (ushort)((u + 0x7FFFu + ((u>>16)&1u))>>16); }
__device__ __forceinline__ uint pack2(float lo, float hi){
    return (uint)f2bf(lo) | ((uint)f2bf(hi)<<16); }

// async global->LDS, 16B per lane; LDS dest = wave-uniform base + lane*16
__device__ __forceinline__ void gll16(const void* g, void* l) {
    __builtin_amdgcn_global_load_lds(
        (const __attribute__((address_space(1))) uint32_t*)g,
        (__attribute__((address_space(3))) uint32_t*)l,
        16, 0, 0);
}

// ---------------- phase A: bin edges by coarse dst bucket, atomic-free ----------------

__global__ __launch_bounds__(256) void binfill_kernel(const int* __restrict__ edges,
                                                      int* __restrict__ runcnt,   // [NBLK_A][NBKT]
                                                      uint* __restrict__ binned) { // [NBKT][NBLK_A][RUNCAP]
    __shared__ int pos[NBKT];
    int blk = blockIdx.x, tid = threadIdx.x;
    for (int i = tid; i < NBKT; i += 256) pos[i] = 0;
    __syncthreads();
    int start = blk * EPB;
    for (int i = tid; i < EPB; i += 256) {
        int e = start + i;
        int src = edges[e * 3];
        int rel = edges[e * 3 + 1];
        int dst = edges[e * 3 + 2];
        int bkt = (rel >= RCONST) + (rel >= 2 * RCONST);
        int b = dst >> 9, off = dst & 511;
        int p = atomicAdd(&pos[b], 1);         // LDS atomic
        if (p < RUNCAP)
            binned[((size_t)b * NBLK_A + blk) * RUNCAP + p] =
                (uint)src | ((uint)bkt << 17) | ((uint)off << 19);
    }
    __syncthreads();
    for (int i = tid; i < NBKT; i += 256)
        runcnt[blk * NBKT + i] = min(pos[i], RUNCAP);
}

// ---------------- merged: scatter (blocks 0..195) + convx + wconv-image x2 ----------------

__global__ __launch_bounds__(256) void scatterx_kernel(
    const uint* __restrict__ binned, const int* __restrict__ runcnt,
    int* __restrict__ elist, uint* __restrict__ segp, float4* __restrict__ cnts,
    const float* __restrict__ x, uint* __restrict__ xb,
    const float* __restrict__ W1, const float* __restrict__ Ws1, uint* __restrict__ Wb1,
    const float* __restrict__ W2, const float* __restrict__ Ws2, uint* __restrict__ Wb2) {
    __shared__ int cnt3[512][4];   // pass1 counts, then segment LIMITS
    __shared__ int cur[512][4];    // pass2 cursors
    int blk = blockIdx.x, tid = threadIdx.x;

    if (blk < NBKT) {
        // ---- scatter: two-pass -> bucket-sorted, pair-padded elist (keeps bkt bits)
        int b = blk;
        int base = b << 9;
        for (int i = tid; i < 512; i += 256) { cnt3[i][0] = 0; cnt3[i][1] = 0; cnt3[i][2] = 0; }
        __syncthreads();
        #pragma unroll
        for (int rr = 0; rr < 2; ++rr) {
            int r = tid * 2 + rr;
            int n = runcnt[r * NBKT + b];
            const uint* p = binned + ((size_t)b * NBLK_A + r) * RUNCAP;
            for (int i = 0; i < n; ++i) {
                uint e = p[i];
                atomicAdd(&cnt3[e >> 19][(e >> 17) & 3], 1);
            }
        }
        __syncthreads();
        for (int i = tid; i < 512; i += 256) {
            int node = base + i;
            if (node >= NPAD) continue;
            int c0 = cnt3[i][0], c1 = cnt3[i][1], c2 = cnt3[i][2];
            int n0 = min((c0 + 1) & ~1, 64);
            int n1 = min((c1 + 1) & ~1, 64 - n0);
            int n2 = min((c2 + 1) & ~1, 64 - n0 - n1);
            int s1 = n0, s2 = n0 + n1;
            cur[i][0] = 0; cur[i][1] = s1; cur[i][2] = s2;
            int* er = elist + (size_t)node * 64;
            for (int j = min(c0, n0); j < n0; ++j) er[j] = ZROW;
            for (int j = min(c1, n1); j < n1; ++j) er[s1 + j] = ZROW;
            for (int j = min(c2, n2); j < n2; ++j) er[s2 + j] = ZROW;
            cnt3[i][0] = s1; cnt3[i][1] = s2; cnt3[i][2] = s2 + n2;   // limits
            segp[node] = (uint)n0 | ((uint)n1 << 8) | ((uint)n2 << 16);
            float4 v;
            v.x = (float)c0; v.y = (float)c1; v.z = (float)c2;
            v.w = 1.0f / fmaxf((float)(c0 + c1 + c2), 1.0f);
            cnts[node] = v;
        }
        __syncthreads();
        #pragma unroll
        for (int rr = 0; rr < 2; ++rr) {
            int r = tid * 2 + rr;
            int n = runcnt[r * NBKT + b];
            const uint* p = binned + ((size_t)b * NBLK_A + r) * RUNCAP;
            for (int i = 0; i < n; ++i) {
                uint e = p[i];
                int off = (int)(e >> 19), bk = (int)((e >> 17) & 3);
                int pos = atomicAdd(&cur[off][bk], 1);
                if (pos < cnt3[off][bk])
                    elist[(size_t)(base + off) * 64 + pos] = (int)(e & 0x7FFFFu);
            }
        }
    } else if (blk < NBKT + NCONVX) {
        // ---- convx: f32 -> bf16 pairs, rows NNODES..NPAD zeroed (ZROW)
        size_t i = (size_t)(blk - NBKT) * 256 + tid;
        if (i < (size_t)NPAD * 64) {
            uint val = 0;
            if (i < (size_t)NNODES * 64) {
                float2 f = *(const float2*)&x[i * 2];
                val = pack2(f.x, f.y);
            }
            xb[i] = val;
        }
    } else {
        // ---- wconv-image: Wb stored as 8 per-chunk LDS images of 16KB.
        // u32 index i = t*4096 + r*32 + s*4 + p; seg s holds k-octet o = s^(r&7);
        // k = t*64 + o*8 + p*2; source: k<384 -> W[k>>7][r][k&127], else Ws[r][k-384].
        int wi = blk - (NBKT + NCONVX);
        const float* W  = (wi < 128) ? W1  : W2;
        const float* Ws = (wi < 128) ? Ws1 : Ws2;
        uint* Wb        = (wi < 128) ? Wb1 : Wb2;
        int i = (wi & 127) * 256 + tid;        // 0..32767
        int r = (i >> 5) & 127;
        int s = (i >> 2) & 7;
        int p = i & 3;
        int o = s ^ (r & 7);
        int k = (i >> 12) * 64 + o * 8 + p * 2;
        float v0, v1;
        if (k < 384) {
            const float* q = W + (k >> 7) * 16384 + r * 128 + (k & 127);
            v0 = q[0]; v1 = q[1];
        } else {
            const float* q = Ws + r * 128 + (k - 384);
            v0 = q[0]; v1 = q[1];
        }
        Wb[i] = pack2(v0, v1);
    }
}

// ---------------- gather: one wave per node, one-hot, writes A in image order ----------------
// Image: per 128-node tile, 6 chunks x 16KB; u32 addr = tile*24576 + t*4096 +
// r*32 + s*4 + (l&3), with t = 2b + (l>>5), o = (l>>2)&7, s = o^(r&7).

__global__ __launch_bounds__(256) void gather_kernel(
    const uint* __restrict__ xbu,      // [NPAD][64] bf16-pairs (+ZROW)
    const uint* __restrict__ segp,     // [NPAD] padded seg lengths
    const int*  __restrict__ elist,    // [NPAD][64] src|bkt<<17, sorted+padded
    const float4* __restrict__ cnts,   // [NPAD] (c0,c1,c2,inv)
    uint* __restrict__ AbImg) {        // [NPAD/128][6][4096] u32 image
    int w = threadIdx.x >> 6, lane = threadIdx.x & 63;
    int node = blockIdx.x * 4 + w;     // grid = NNODES/4 exactly
    uint sp = __builtin_amdgcn_readfirstlane(segp[node]);
    int tot = (int)(sp & 255) + (int)((sp >> 8) & 255) + (int)((sp >> 16) & 255);
    float inv = cnts[node].w;
    int ve = elist[(size_t)node * 64 + lane];

    float a0l = 0.f, a0h = 0.f, a1l = 0.f, a1h = 0.f, a2l = 0.f, a2h = 0.f;
    int j = 0;
    for (; j + 4 <= tot; j += 4) {
        int e0 = __builtin_amdgcn_readlane(ve, j);
        int e1 = __builtin_amdgcn_readlane(ve, j + 1);
        int e2 = __builtin_amdgcn_readlane(ve, j + 2);
        int e3 = __builtin_amdgcn_readlane(ve, j + 3);
        int s0 = e0 & 0x1FFFF, k0 = e0 >> 17;
        int s1 = e1 & 0x1FFFF, k1 = e1 >> 17;
        int s2 = e2 & 0x1FFFF, k2 = e2 >> 17;
        int s3 = e3 & 0x1FFFF, k3 = e3 >> 17;
        uint u0 = xbu[((size_t)s0 << 6) + lane];
        uint u1 = xbu[((size_t)s1 << 6) + lane];
        uint u2 = xbu[((size_t)s2 << 6) + lane];
        uint u3 = xbu[((size_t)s3 << 6) + lane];

        float q00 = (k0 == 0) ? 1.f : 0.f, q01 = (k0 == 1) ? 1.f : 0.f, q02 = (k0 == 2) ? 1.f : 0.f;
        float q10 = (k1 == 0) ? 1.f : 0.f, q11 = (k1 == 1) ? 1.f : 0.f, q12 = (k1 == 2) ? 1.f : 0.f;
        float q20 = (k2 == 0) ? 1.f : 0.f, q21 = (k2 == 1) ? 1.f : 0.f, q22 = (k2 == 2) ? 1.f : 0.f;
        float q30 = (k3 == 0) ? 1.f : 0.f, q31 = (k3 == 1) ? 1.f : 0.f, q32 = (k3 == 2) ? 1.f : 0.f;

        float f0l = bflo(u0), f0h = bfhi(u0);
        float f1l = bflo(u1), f1h = bfhi(u1);
        float f2l = bflo(u2), f2h = bfhi(u2);
        float f3l = bflo(u3), f3h = bfhi(u3);

        a0l = fmaf(q00, f0l, a0l); a1l = fmaf(q01, f0l, a1l); a2l = fmaf(q02, f0l, a2l);
        a0h = fmaf(q00, f0h, a0h); a1h = fmaf(q01, f0h, a1h); a2h = fmaf(q02, f0h, a2h);
        a0l = fmaf(q10, f1l, a0l); a1l = fmaf(q11, f1l, a1l); a2l = fmaf(q12, f1l, a2l);
        a0h = fmaf(q10, f1h, a0h); a1h = fmaf(q11, f1h, a1h); a2h = fmaf(q12, f1h, a2h);
        a0l = fmaf(q20, f2l, a0l); a1l = fmaf(q21, f2l, a1l); a2l = fmaf(q22, f2l, a2l);
        a0h = fmaf(q20, f2h, a0h); a1h = fmaf(q21, f2h, a1h); a2h = fmaf(q22, f2h, a2h);
        a0l = fmaf(q30, f3l, a0l); a1l = fmaf(q31, f3l, a1l); a2l = fmaf(q32, f3l, a2l);
        a0h = fmaf(q30, f3h, a0h); a1h = fmaf(q31, f3h, a1h); a2h = fmaf(q32, f3h, a2h);
    }
    if (j < tot) {                     // pair-padded: exactly 2 remain
        int e0 = __builtin_amdgcn_readlane(ve, j);
        int e1 = __builtin_amdgcn_readlane(ve, j + 1);
        int s0 = e0 & 0x1FFFF, k0 = e0 >> 17;
        int s1 = e1 & 0x1FFFF, k1 = e1 >> 17;
        uint u0 = xbu[((size_t)s0 << 6) + lane];
        uint u1 = xbu[((size_t)s1 << 6) + lane];
        float q00 = (k0 == 0) ? 1.f : 0.f, q01 = (k0 == 1) ? 1.f : 0.f, q02 = (k0 == 2) ? 1.f : 0.f;
        float q10 = (k1 == 0) ? 1.f : 0.f, q11 = (k1 == 1) ? 1.f : 0.f, q12 = (k1 == 2) ? 1.f : 0.f;
        float f0l = bflo(u0), f0h = bfhi(u0);
        float f1l = bflo(u1), f1h = bfhi(u1);
        a0l = fmaf(q00, f0l, a0l); a1l = fmaf(q01, f0l, a1l); a2l = fmaf(q02, f0l, a2l);
        a0h = fmaf(q00, f0h, a0h); a1h = fmaf(q01, f0h, a1h); a2h = fmaf(q02, f0h, a2h);
        a0l = fmaf(q10, f1l, a0l); a1l = fmaf(q11, f1l, a1l); a2l = fmaf(q12, f1l, a2l);
        a0h = fmaf(q10, f1h, a0h); a1h = fmaf(q11, f1h, a1h); a2h = fmaf(q12, f1h, a2h);
    }

    int r = node & 127;
    size_t tb = (size_t)(node >> 7) * 24576;
    int o = (lane >> 2) & 7;
    int half = lane >> 5;
    int li = lane & 3;
    size_t a0 = tb + (size_t)(0 + half) * 4096 + r * 32 + (o ^ (r & 7)) * 4 + li;
    size_t a1 = tb + (size_t)(2 + half) * 4096 + r * 32 + (o ^ (r & 7)) * 4 + li;
    size_t a2 = tb + (size_t)(4 + half) * 4096 + r * 32 + (o ^ (r & 7)) * 4 + li;
    AbImg[a0] = pack2(a0l * inv, a0h * inv);
    AbImg[a1] = pack2(a1l * inv, a1h * inv);
    AbImg[a2] = pack2(a2l * inv, a2h * inv);
}

// ---------------- MFMA GEMM + fused epilogue: global_load_lds staging ----------------
// 512 threads = 8 waves (2 M x 4 N); block tile 128x128; wave tile 64x32.
// Chunks 0..5: A,B staged by global_load_lds dwordx4 from pre-swizzled images
// (linear LDS dest, 1KB per wave-instr, fully coalesced) -- no VGPR round-trip.
// Chunks 6,7: A from xb (row-major, needed by gather) preloaded into regs at
// kernel start, ds_written with the image swizzle; B still via gll.
// Read side identical to round-9 (verified passing).

template<bool OUT_BF16>
__global__ __launch_bounds__(512, 2) void gemm_kernel(
    const uint* __restrict__ AbImg,    // [NPAD/128][6][4096] u32
    const ushort* __restrict__ xb,     // [NPAD][128]
    const uint* __restrict__ WbImg,    // [8][4096] u32
    const float* __restrict__ bia,     // [3][128]
    const float* __restrict__ bs,
    const float* __restrict__ g,
    const float* __restrict__ be,
    const float4* __restrict__ cnts,   // [NPAD] (c0,c1,c2,inv)
    void* __restrict__ out) {
    __shared__ __attribute__((aligned(16))) ushort lA[128 * 64];   // 16 KB image
    __shared__ __attribute__((aligned(16))) ushort lB[128 * 64];   // 16 KB image
    __shared__ float sS1[4][128], sS2[4][128];
    __shared__ float sMean[128], sRstd[128];

    int tid = threadIdx.x;
    int w = tid >> 6, lane = tid & 63;
    int wm = w >> 2, wn = w & 3;       // 2 m-waves x 4 n-waves
    int quad = lane >> 4, l15 = lane & 15;
    int node0 = blockIdx.x * 128;

    int srow = tid >> 2, sseg = (tid & 3) * 2;  // x-chunk reg staging mapping
    uint swzS = (uint)((srow & 7) << 4);
    uint swzR = (uint)((l15 & 7) << 4);

    // preload x chunks (t=6,7) into regs; consumed long after issue
    uint4 rx[2][2];
    {
        const ushort* gX = xb + (size_t)node0 * 128;
        #pragma unroll
        for (int c = 0; c < 2; ++c) {
            const ushort* pa = gX + (size_t)srow * 128 + c * 64 + sseg * 8;
            rx[c][0] = *(const uint4*)(pa);
            rx[c][1] = *(const uint4*)(pa + 8);
        }
    }

    const char* aimg = (const char*)(AbImg + (size_t)blockIdx.x * 24576);
    const char* bimg = (const char*)WbImg;
    char* ldsA = (char*)lA + w * 2048;
    char* ldsB = (char*)lB + w * 2048;
    int loff = w * 2048 + lane * 16;

    f32x4 accm[4][2], accq[4][2];
    f32x4 zero = {0.f, 0.f, 0.f, 0.f};
    #pragma unroll
    for (int i = 0; i < 4; ++i)
        #pragma unroll
        for (int j = 0; j < 2; ++j) { accm[i][j] = zero; accq[i][j] = zero; }

    auto compute = [&](f32x4 (&acc)[4][2]) {
        #pragma unroll
        for (int ks = 0; ks < 2; ++ks) {
            short8 aF[4], bF[2];
            #pragma unroll
            for (int mt = 0; mt < 4; ++mt) {
                int row = wm * 64 + mt * 16 + l15;
                aF[mt] = *(const short8*)((const char*)lA + row * 128 +
                                          (((uint)(ks * 64 + quad * 16)) ^ swzR));
            }
            #pragma unroll
            for (int nt = 0; nt < 2; ++nt) {
                int row = wn * 32 + nt * 16 + l15;
                bF[nt] = *(const short8*)((const char*)lB + row * 128 +
                                          (((uint)(ks * 64 + quad * 16)) ^ swzR));
            }
            #pragma unroll
            for (int mt = 0; mt < 4; ++mt)
                #pragma unroll
                for (int nt = 0; nt < 2; ++nt)
                    acc[mt][nt] = __builtin_amdgcn_mfma_f32_16x16x32_bf16(
                        aF[mt], bF[nt], acc[mt][nt], 0, 0, 0);
        }
    };

    #pragma unroll
    for (int t = 0; t < 8; ++t) {
        if (t) __syncthreads();                 // prev compute's LDS reads done
        if (t < 6) {
            gll16(aimg + t * 16384 + loff,        ldsA);
            gll16(aimg + t * 16384 + loff + 1024, ldsA + 1024);
        } else {
            int c = t - 6;
            char* bA = (char*)lA + srow * 128;
            *(uint4*)(bA + (((uint)(sseg * 16)) ^ swzS))       = rx[c][0];
            *(uint4*)(bA + (((uint)((sseg + 1) * 16)) ^ swzS)) = rx[c][1];
        }
        gll16(bimg + t * 16384 + loff,        ldsB);
        gll16(bimg + t * 16384 + loff + 1024, ldsB + 1024);
        __syncthreads();                        // drains vmcnt+lgkm: images ready
        if (t < 6) compute(accm); else compute(accq);
    }

    // epilogue: v = relu(accm + bias_msg) + accq + bs, then LN over 128 cols
    int nl0 = wn * 32 + l15;
    float pb0[2], pb1[2], pb2[2], pbs[2], pg[2], pbe[2];
    #pragma unroll
    for (int nt = 0; nt < 2; ++nt) {
        int nl = nl0 + nt * 16;
        pb0[nt] = bia[nl]; pb1[nt] = bia[128 + nl]; pb2[nt] = bia[256 + nl];
        pbs[nt] = bs[nl];  pg[nt] = g[nl];          pbe[nt] = be[nl];
    }
    #pragma unroll
    for (int mt = 0; mt < 4; ++mt) {
        #pragma unroll
        for (int r = 0; r < 4; ++r) {
            int ml = wm * 64 + mt * 16 + quad * 4 + r;
            float4 c4 = cnts[node0 + ml];
            float s1 = 0.f, s2 = 0.f;
            #pragma unroll
            for (int nt = 0; nt < 2; ++nt) {
                float bd = (c4.x * pb0[nt] + c4.y * pb1[nt] + c4.z * pb2[nt]) * c4.w;
                float v = fmaxf(accm[mt][nt][r] + bd, 0.f) + accq[mt][nt][r] + pbs[nt];
                accm[mt][nt][r] = v;
                s1 += v; s2 += v * v;
            }
            #pragma unroll
            for (int mask = 1; mask < 16; mask <<= 1) {
                s1 += __shfl_xor(s1, mask);
                s2 += __shfl_xor(s2, mask);
            }
            if (l15 == 0) { sS1[wn][ml] = s1; sS2[wn][ml] = s2; }
        }
    }
    __syncthreads();
    if (tid < 128) {
        float s1 = sS1[0][tid] + sS1[1][tid] + sS1[2][tid] + sS1[3][tid];
        float s2 = sS2[0][tid] + sS2[1][tid] + sS2[2][tid] + sS2[3][tid];
        float mean = s1 * (1.f / 128.f);
        float var = s2 * (1.f / 128.f) - mean * mean;
        sMean[tid] = mean;
        sRstd[tid] = rsqrtf(var + 1e-5f);
    }
    __syncthreads();
    #pragma unroll
    for (int mt = 0; mt < 4; ++mt) {
        #pragma unroll
        for (int r = 0; r < 4; ++r) {
            int ml = wm * 64 + mt * 16 + quad * 4 + r;
            int node = node0 + ml;
            float mn = sMean[ml], rs = sRstd[ml];
            #pragma unroll
            for (int nt = 0; nt < 2; ++nt) {
                float v = (accm[mt][nt][r] - mn) * rs * pg[nt] + pbe[nt];
                if (OUT_BF16) {
                    float vh = __shfl_xor(v, 1);
                    if (!(l15 & 1)) {
                        // pad rows (node >= NNODES) written as zeros: they back
                        // ZROW reads in the next layer's gather.
                        uint val = (node < NNODES) ? pack2(v, vh) : 0u;
                        uint* o = (uint*)out;
                        o[(size_t)node * 64 + wn * 16 + nt * 8 + (l15 >> 1)] = val;
                    }
                } else {
                    if (node < NNODES) {
                        float* o = (float*)out;
                        o[(size_t)node * 128 + nl0 + nt * 16] = v;
                    }
                }
            }
        }
    }
}

// ---------------- launch ----------------

extern "C" void kernel_launch(void* const* d_in, const int* in_sizes, int n_in,
                              void* d_out, int out_size, void* d_ws, size_t ws_size,
                              hipStream_t stream) {
    (void)in_sizes; (void)n_in; (void)out_size; (void)ws_size;

    const int*   edges = (const int*)d_in[0];
    const float* xemb  = (const float*)d_in[1];
    const float* W1  = (const float*)d_in[2];
    const float* b1  = (const float*)d_in[3];
    const float* Ws1 = (const float*)d_in[4];
    const float* bs1 = (const float*)d_in[5];
    const float* g1  = (const float*)d_in[6];
    const float* be1 = (const float*)d_in[7];
    const float* W2  = (const float*)d_in[8];
    const float* b2  = (const float*)d_in[9];
    const float* Ws2 = (const float*)d_in[10];
    const float* bs2 = (const float*)d_in[11];
    const float* g2  = (const float*)d_in[12];
    const float* be2 = (const float*)d_in[13];

    char* ws = (char*)d_ws;
    auto take = [&](size_t bytes) {
        char* p = ws;
        ws += (bytes + 255) & ~(size_t)255;
        return p;
    };
    int*    elist  = (int*)take((size_t)NPAD * CAP * 4);
    uint*   segp   = (uint*)take((size_t)NPAD * 4);
    float4* cnts   = (float4*)take((size_t)NPAD * 16);
    uint*   xb0    = (uint*)take((size_t)NPAD * 128 * 2);
    uint*   xb1    = (uint*)take((size_t)NPAD * 128 * 2);
    uint*   AbImg  = (uint*)take((size_t)NPAD * 384 * 2);   // 782 tiles x 6 x 16KB
    uint*   Wb1    = (uint*)take((size_t)128 * 512 * 2);
    uint*   Wb2    = (uint*)take((size_t)128 * 512 * 2);
    int*    runcnt = (int*)take((size_t)NBLK_A * NBKT * 4);
    uint*   binned = (uint*)take((size_t)NBKT * NBLK_A * RUNCAP * 4);

    binfill_kernel<<<NBLK_A, 256, 0, stream>>>(edges, runcnt, binned);
    scatterx_kernel<<<NBKT + NCONVX + 256, 256, 0, stream>>>(
        binned, runcnt, elist, segp, cnts,
        xemb, xb0, W1, Ws1, Wb1, W2, Ws2, Wb2);

    gather_kernel<<<NNODES / 4, 256, 0, stream>>>(xb0, segp, elist, cnts, AbImg);
    gemm_kernel<true><<<NPAD / 128, 512, 0, stream>>>(
        AbImg, (const ushort*)xb0, Wb1,
        b1, bs1, g1, be1, cnts, xb1);

    gather_kernel<<<NNODES / 4, 256, 0, stream>>>(xb1, segp, elist, cnts, AbImg);
    gemm_kernel<false><<<NPAD / 128, 512, 0, stream>>>(
        AbImg, (const ushort*)xb1, Wb2,
        b2, bs2, g2, be2, cnts, d_out);
}

// Round 11
// 389.240 us; speedup vs baseline: 1.0553x; 1.0553x over previous
//
#include <hip/hip_runtime.h>
#include <stdint.h>

typedef unsigned int uint;
typedef unsigned short ushort;

#define NNODES 100000
#define NPAD   100096          // NNODES rounded up to 128
#define NEDGES 1600000
#define RCONST 400
#define CAP    64              // fixed per-node edge capacity
#define ZROW   NNODES          // guaranteed-zero row in xb0/xb1, used for segment padding

// atomic-free binned CSR build
#define NBKT   196             // ceil(NPAD / 512)
#define NBLK_A 512             // binfill blocks
#define EPB    3125            // NEDGES / NBLK_A, exact
#define RUNCAP 64              // per-(block,bucket) slot capacity; mean 16, P(>64)~2e-18
#define NCONVX 25024           // NPAD*64/256

typedef __attribute__((ext_vector_type(8))) short short8;
typedef __attribute__((ext_vector_type(4))) float f32x4;

__device__ __forceinline__ float bflo(uint u){ union{uint i;float f;}c; c.i=u<<16; return c.f; }
__device__ __forceinline__ float bfhi(uint u){ union{uint i;float f;}c; c.i=u&0xFFFF0000u; return c.f; }
__device__ __forceinline__ ushort f2bf(float f){ union{uint i;float ff;}c; c.ff=f; uint u=c.i;
    return (ushort)((u + 0x7FFFu + ((u>>16)&1u))>>16); }
__device__ __forceinline__ uint pack2(float lo, float hi){
    return (uint)f2bf(lo) | ((uint)f2bf(hi)<<16); }

// ---------------- phase A: bin edges by coarse dst bucket, atomic-free ----------------

__global__ __launch_bounds__(256) void binfill_kernel(const int* __restrict__ edges,
                                                      int* __restrict__ runcnt,   // [NBLK_A][NBKT]
                                                      uint* __restrict__ binned) { // [NBKT][NBLK_A][RUNCAP]
    __shared__ int pos[NBKT];
    int blk = blockIdx.x, tid = threadIdx.x;
    for (int i = tid; i < NBKT; i += 256) pos[i] = 0;
    __syncthreads();
    int start = blk * EPB;
    for (int i = tid; i < EPB; i += 256) {
        int e = start + i;
        int src = edges[e * 3];
        int rel = edges[e * 3 + 1];
        int dst = edges[e * 3 + 2];
        int bkt = (rel >= RCONST) + (rel >= 2 * RCONST);
        int b = dst >> 9, off = dst & 511;
        int p = atomicAdd(&pos[b], 1);         // LDS atomic
        if (p < RUNCAP)
            binned[((size_t)b * NBLK_A + blk) * RUNCAP + p] =
                (uint)src | ((uint)bkt << 17) | ((uint)off << 19);
    }
    __syncthreads();
    for (int i = tid; i < NBKT; i += 256)
        runcnt[blk * NBKT + i] = min(pos[i], RUNCAP);
}

// ---------------- merged: scatter (blocks 0..195) + convx + wconv x2 ----------------
// Scatter run drains vectorized: uint4 = 4 entries/load (runs are 256B-aligned,
// reads past n stay inside the run; per-entry tail guards).

__global__ __launch_bounds__(256) void scatterx_kernel(
    const uint* __restrict__ binned, const int* __restrict__ runcnt,
    int* __restrict__ elist, uint* __restrict__ segp, float4* __restrict__ cnts,
    const float* __restrict__ x, uint* __restrict__ xb,
    const float* __restrict__ W1, const float* __restrict__ Ws1, uint* __restrict__ Wb1,
    const float* __restrict__ W2, const float* __restrict__ Ws2, uint* __restrict__ Wb2) {
    __shared__ int cnt3[512][4];   // pass1 counts, then segment LIMITS
    __shared__ int cur[512][4];    // pass2 cursors
    int blk = blockIdx.x, tid = threadIdx.x;

    if (blk < NBKT) {
        int b = blk;
        int base = b << 9;
        for (int i = tid; i < 512; i += 256) { cnt3[i][0] = 0; cnt3[i][1] = 0; cnt3[i][2] = 0; }
        __syncthreads();
        // pass 1: count (4 entries per load)
        #pragma unroll
        for (int rr = 0; rr < 2; ++rr) {
            int r = tid * 2 + rr;
            int n = runcnt[r * NBKT + b];
            const uint* p = binned + ((size_t)b * NBLK_A + r) * RUNCAP;
            for (int i = 0; i < n; i += 4) {
                uint4 e4 = *(const uint4*)(p + i);
                atomicAdd(&cnt3[e4.x >> 19][(e4.x >> 17) & 3], 1);
                if (i + 1 < n) atomicAdd(&cnt3[e4.y >> 19][(e4.y >> 17) & 3], 1);
                if (i + 2 < n) atomicAdd(&cnt3[e4.z >> 19][(e4.z >> 17) & 3], 1);
                if (i + 3 < n) atomicAdd(&cnt3[e4.w >> 19][(e4.w >> 17) & 3], 1);
            }
        }
        __syncthreads();
        // per-node: starts, dummy padding, metadata
        for (int i = tid; i < 512; i += 256) {
            int node = base + i;
            if (node >= NPAD) continue;
            int c0 = cnt3[i][0], c1 = cnt3[i][1], c2 = cnt3[i][2];
            int n0 = min((c0 + 1) & ~1, 64);
            int n1 = min((c1 + 1) & ~1, 64 - n0);
            int n2 = min((c2 + 1) & ~1, 64 - n0 - n1);
            int s1 = n0, s2 = n0 + n1;
            cur[i][0] = 0; cur[i][1] = s1; cur[i][2] = s2;
            int* er = elist + (size_t)node * 64;
            for (int j = min(c0, n0); j < n0; ++j) er[j] = ZROW;
            for (int j = min(c1, n1); j < n1; ++j) er[s1 + j] = ZROW;
            for (int j = min(c2, n2); j < n2; ++j) er[s2 + j] = ZROW;
            cnt3[i][0] = s1; cnt3[i][1] = s2; cnt3[i][2] = s2 + n2;   // limits
            segp[node] = (uint)n0 | ((uint)n1 << 8) | ((uint)n2 << 16);
            float4 v;
            v.x = (float)c0; v.y = (float)c1; v.z = (float)c2;
            v.w = 1.0f / fmaxf((float)(c0 + c1 + c2), 1.0f);
            cnts[node] = v;
        }
        __syncthreads();
        // pass 2: place (4 entries per load; keeps bkt bits in entry)
        #pragma unroll
        for (int rr = 0; rr < 2; ++rr) {
            int r = tid * 2 + rr;
            int n = runcnt[r * NBKT + b];
            const uint* p = binned + ((size_t)b * NBLK_A + r) * RUNCAP;
            for (int i = 0; i < n; i += 4) {
                uint4 e4 = *(const uint4*)(p + i);
                uint es[4] = { e4.x, e4.y, e4.z, e4.w };
                #pragma unroll
                for (int k = 0; k < 4; ++k) {
                    if (i + k < n) {
                        uint e = es[k];
                        int off = (int)(e >> 19), bk = (int)((e >> 17) & 3);
                        int pos = atomicAdd(&cur[off][bk], 1);
                        if (pos < cnt3[off][bk])
                            elist[(size_t)(base + off) * 64 + pos] = (int)(e & 0x7FFFFu);
                    }
                }
            }
        }
    } else if (blk < NBKT + NCONVX) {
        // ---- convx: f32 -> bf16 pairs, rows NNODES..NPAD zeroed (ZROW)
        size_t i = (size_t)(blk - NBKT) * 256 + tid;
        if (i < (size_t)NPAD * 64) {
            uint val = 0;
            if (i < (size_t)NNODES * 64) {
                float2 f = *(const float2*)&x[i * 2];
                val = pack2(f.x, f.y);
            }
            xb[i] = val;
        }
    } else {
        // ---- wconv: Wb[n][k] bf16; k<384: W[k>>7][n][k&127]; k>=384: Ws[n][k-384]
        int wi = blk - (NBKT + NCONVX);
        const float* W  = (wi < 128) ? W1  : W2;
        const float* Ws = (wi < 128) ? Ws1 : Ws2;
        uint* Wb        = (wi < 128) ? Wb1 : Wb2;
        int i = (wi & 127) * 256 + tid;
        int n = i >> 8, kp = i & 255, k = kp * 2;
        float v0, v1;
        if (k < 384) {
            int r = k >> 7, kk = k & 127;
            const float* p = W + r * 16384 + n * 128 + kk;
            v0 = p[0]; v1 = p[1];
        } else {
            const float* p = Ws + n * 128 + (k - 384);
            v0 = p[0]; v1 = p[1];
        }
        Wb[i] = pack2(v0, v1);
    }
}

// ---------------- gather: one wave per node, round-4 one-hot (counter-free) ----------------

__global__ __launch_bounds__(256) void gather_kernel(
    const uint* __restrict__ xbu,      // [NPAD][64] bf16-pairs (+ZROW)
    const uint* __restrict__ segp,     // [NPAD] padded seg lengths
    const int*  __restrict__ elist,    // [NPAD][64] src|bkt<<17, sorted+padded
    const float4* __restrict__ cnts,   // [NPAD] (c0,c1,c2,inv)
    uint* __restrict__ Ab) {           // [NPAD][192] bf16-pairs
    int w = threadIdx.x >> 6, lane = threadIdx.x & 63;
    int node = blockIdx.x * 4 + w;     // grid = NNODES/4 exactly
    uint sp = __builtin_amdgcn_readfirstlane(segp[node]);
    int tot = (int)(sp & 255) + (int)((sp >> 8) & 255) + (int)((sp >> 16) & 255);
    float inv = cnts[node].w;
    int ve = elist[(size_t)node * 64 + lane];

    float a0l = 0.f, a0h = 0.f, a1l = 0.f, a1h = 0.f, a2l = 0.f, a2h = 0.f;
    int j = 0;
    for (; j + 4 <= tot; j += 4) {
        int e0 = __builtin_amdgcn_readlane(ve, j);
        int e1 = __builtin_amdgcn_readlane(ve, j + 1);
        int e2 = __builtin_amdgcn_readlane(ve, j + 2);
        int e3 = __builtin_amdgcn_readlane(ve, j + 3);
        int s0 = e0 & 0x1FFFF, k0 = e0 >> 17;
        int s1 = e1 & 0x1FFFF, k1 = e1 >> 17;
        int s2 = e2 & 0x1FFFF, k2 = e2 >> 17;
        int s3 = e3 & 0x1FFFF, k3 = e3 >> 17;
        uint u0 = xbu[((size_t)s0 << 6) + lane];
        uint u1 = xbu[((size_t)s1 << 6) + lane];
        uint u2 = xbu[((size_t)s2 << 6) + lane];
        uint u3 = xbu[((size_t)s3 << 6) + lane];

        float q00 = (k0 == 0) ? 1.f : 0.f, q01 = (k0 == 1) ? 1.f : 0.f, q02 = (k0 == 2) ? 1.f : 0.f;
        float q10 = (k1 == 0) ? 1.f : 0.f, q11 = (k1 == 1) ? 1.f : 0.f, q12 = (k1 == 2) ? 1.f : 0.f;
        float q20 = (k2 == 0) ? 1.f : 0.f, q21 = (k2 == 1) ? 1.f : 0.f, q22 = (k2 == 2) ? 1.f : 0.f;
        float q30 = (k3 == 0) ? 1.f : 0.f, q31 = (k3 == 1) ? 1.f : 0.f, q32 = (k3 == 2) ? 1.f : 0.f;

        float f0l = bflo(u0), f0h = bfhi(u0);
        float f1l = bflo(u1), f1h = bfhi(u1);
        float f2l = bflo(u2), f2h = bfhi(u2);
        float f3l = bflo(u3), f3h = bfhi(u3);

        a0l = fmaf(q00, f0l, a0l); a1l = fmaf(q01, f0l, a1l); a2l = fmaf(q02, f0l, a2l);
        a0h = fmaf(q00, f0h, a0h); a1h = fmaf(q01, f0h, a1h); a2h = fmaf(q02, f0h, a2h);
        a0l = fmaf(q10, f1l, a0l); a1l = fmaf(q11, f1l, a1l); a2l = fmaf(q12, f1l, a2l);
        a0h = fmaf(q10, f1h, a0h); a1h = fmaf(q11, f1h, a1h); a2h = fmaf(q12, f1h, a2h);
        a0l = fmaf(q20, f2l, a0l); a1l = fmaf(q21, f2l, a1l); a2l = fmaf(q22, f2l, a2l);
        a0h = fmaf(q20, f2h, a0h); a1h = fmaf(q21, f2h, a1h); a2h = fmaf(q22, f2h, a2h);
        a0l = fmaf(q30, f3l, a0l); a1l = fmaf(q31, f3l, a1l); a2l = fmaf(q32, f3l, a2l);
        a0h = fmaf(q30, f3h, a0h); a1h = fmaf(q31, f3h, a1h); a2h = fmaf(q32, f3h, a2h);
    }
    if (j < tot) {                     // pair-padded: exactly 2 remain
        int e0 = __builtin_amdgcn_readlane(ve, j);
        int e1 = __builtin_amdgcn_readlane(ve, j + 1);
        int s0 = e0 & 0x1FFFF, k0 = e0 >> 17;
        int s1 = e1 & 0x1FFFF, k1 = e1 >> 17;
        uint u0 = xbu[((size_t)s0 << 6) + lane];
        uint u1 = xbu[((size_t)s1 << 6) + lane];
        float q00 = (k0 == 0) ? 1.f : 0.f, q01 = (k0 == 1) ? 1.f : 0.f, q02 = (k0 == 2) ? 1.f : 0.f;
        float q10 = (k1 == 0) ? 1.f : 0.f, q11 = (k1 == 1) ? 1.f : 0.f, q12 = (k1 == 2) ? 1.f : 0.f;
        float f0l = bflo(u0), f0h = bfhi(u0);
        float f1l = bflo(u1), f1h = bfhi(u1);
        a0l = fmaf(q00, f0l, a0l); a1l = fmaf(q01, f0l, a1l); a2l = fmaf(q02, f0l, a2l);
        a0h = fmaf(q00, f0h, a0h); a1h = fmaf(q01, f0h, a1h); a2h = fmaf(q02, f0h, a2h);
        a0l = fmaf(q10, f1l, a0l); a1l = fmaf(q11, f1l, a1l); a2l = fmaf(q12, f1l, a2l);
        a0h = fmaf(q10, f1h, a0h); a1h = fmaf(q11, f1h, a1h); a2h = fmaf(q12, f1h, a2h);
    }

    size_t ab = (size_t)node * 192 + lane;
    Ab[ab]       = pack2(a0l * inv, a0h * inv);
    Ab[ab + 64]  = pack2(a1l * inv, a1h * inv);
    Ab[ab + 128] = pack2(a2l * inv, a2h * inv);
}

// ---------------- MFMA GEMM + fused epilogue: 128-row tile, double-buffered LDS ----------------
// 512 threads = 8 waves (2 M x 4 N); block tile 128x128; wave tile 64x32.
// K-chunk 64, DOUBLE-buffered LDS -> ONE barrier per chunk (was 2): chunk t's
// write targets buf[t&1], last read by compute(t-2), fenced by iteration t-1's
// barrier. Prefetch (load_chunk t+1) issues AFTER the barrier so it rides under
// compute(t) and drains harmlessly at the next write's vmcnt wait.
// LDS XOR-swizzle -> conflict-free ds_read_b128 (0 conflicts, r4-r9).

template<bool OUT_BF16>
__global__ __launch_bounds__(512, 2) void gemm_kernel(
    const ushort* __restrict__ Ab,     // [NPAD][384]
    const ushort* __restrict__ xb,     // [NPAD][128]
    const ushort* __restrict__ Wb,     // [128][512]
    const float* __restrict__ bia,     // [3][128]
    const float* __restrict__ bs,
    const float* __restrict__ g,
    const float* __restrict__ be,
    const float4* __restrict__ cnts,   // [NPAD] (c0,c1,c2,inv)
    void* __restrict__ out) {
    __shared__ ushort lA[2][128 * 64];   // 2 x 16 KB, swizzled rows of 128 B
    __shared__ ushort lB[2][128 * 64];   // 2 x 16 KB
    __shared__ float sS1[4][128], sS2[4][128];
    __shared__ float sMean[128], sRstd[128];

    int tid = threadIdx.x;
    int w = tid >> 6, lane = tid & 63;
    int wm = w >> 2, wn = w & 3;       // 2 m-waves x 4 n-waves
    int quad = lane >> 4, l15 = lane & 15;
    int node0 = blockIdx.x * 128;

    int srow = tid >> 2, sseg = (tid & 3) * 2;  // 128 rows x 8 segs(16B); 2 A + 2 B segs/thread
    uint swzS = (uint)((srow & 7) << 4);
    uint swzR = (uint)((l15 & 7) << 4);

    const ushort* gA = Ab + (size_t)node0 * 384;
    const ushort* gX = xb + (size_t)node0 * 128;

    f32x4 accm[4][2], accq[4][2];
    f32x4 zero = {0.f, 0.f, 0.f, 0.f};
    #pragma unroll
    for (int i = 0; i < 4; ++i)
        #pragma unroll
        for (int j = 0; j < 2; ++j) { accm[i][j] = zero; accq[i][j] = zero; }

    uint4 ra0, ra1, rb0, rb1;
    auto load_chunk = [&](int t) {
        const ushort* srcA; size_t strA;
        if (t < 6) { srcA = gA + t * 64;       strA = 384; }
        else       { srcA = gX + (t - 6) * 64; strA = 128; }
        const ushort* pa = srcA + (size_t)srow * strA + sseg * 8;
        ra0 = *(const uint4*)(pa);
        ra1 = *(const uint4*)(pa + 8);
        const ushort* pb = Wb + t * 64 + (size_t)srow * 512 + sseg * 8;
        rb0 = *(const uint4*)(pb);
        rb1 = *(const uint4*)(pb + 8);
    };
    auto compute = [&](f32x4 (&acc)[4][2], int cb) {
        #pragma unroll
        for (int ks = 0; ks < 2; ++ks) {
            short8 aF[4], bF[2];
            #pragma unroll
            for (int mt = 0; mt < 4; ++mt) {
                int row = wm * 64 + mt * 16 + l15;
                aF[mt] = *(const short8*)((const char*)lA[cb] + row * 128 +
                                          (((uint)(ks * 64 + quad * 16)) ^ swzR));
            }
            #pragma unroll
            for (int nt = 0; nt < 2; ++nt) {
                int row = wn * 32 + nt * 16 + l15;
                bF[nt] = *(const short8*)((const char*)lB[cb] + row * 128 +
                                          (((uint)(ks * 64 + quad * 16)) ^ swzR));
            }
            #pragma unroll
            for (int mt = 0; mt < 4; ++mt)
                #pragma unroll
                for (int nt = 0; nt < 2; ++nt)
                    acc[mt][nt] = __builtin_amdgcn_mfma_f32_16x16x32_bf16(
                        aF[mt], bF[nt], acc[mt][nt], 0, 0, 0);
        }
    };

    load_chunk(0);
    #pragma unroll
    for (int t = 0; t < 8; ++t) {
        int cb = t & 1;
        {
            char* bA = (char*)lA[cb] + srow * 128;
            *(uint4*)(bA + (((uint)(sseg * 16)) ^ swzS))       = ra0;
            *(uint4*)(bA + (((uint)((sseg + 1) * 16)) ^ swzS)) = ra1;
            char* bB = (char*)lB[cb] + srow * 128;
            *(uint4*)(bB + (((uint)(sseg * 16)) ^ swzS))       = rb0;
            *(uint4*)(bB + (((uint)((sseg + 1) * 16)) ^ swzS)) = rb1;
        }
        __syncthreads();                // buf[cb] complete; also fences buf[cb^1] readers
        if (t < 7) load_chunk(t + 1);   // prefetch rides under compute(t)
        if (t < 6) compute(accm, cb); else compute(accq, cb);
    }

    // epilogue: v = relu(accm + bias_msg) + accq + bs, then LN over 128 cols
    int nl0 = wn * 32 + l15;
    float pb0[2], pb1[2], pb2[2], pbs[2], pg[2], pbe[2];
    #pragma unroll
    for (int nt = 0; nt < 2; ++nt) {
        int nl = nl0 + nt * 16;
        pb0[nt] = bia[nl]; pb1[nt] = bia[128 + nl]; pb2[nt] = bia[256 + nl];
        pbs[nt] = bs[nl];  pg[nt] = g[nl];          pbe[nt] = be[nl];
    }
    #pragma unroll
    for (int mt = 0; mt < 4; ++mt) {
        #pragma unroll
        for (int r = 0; r < 4; ++r) {
            int ml = wm * 64 + mt * 16 + quad * 4 + r;
            float4 c4 = cnts[node0 + ml];
            float s1 = 0.f, s2 = 0.f;
            #pragma unroll
            for (int nt = 0; nt < 2; ++nt) {
                float bd = (c4.x * pb0[nt] + c4.y * pb1[nt] + c4.z * pb2[nt]) * c4.w;
                float v = fmaxf(accm[mt][nt][r] + bd, 0.f) + accq[mt][nt][r] + pbs[nt];
                accm[mt][nt][r] = v;
                s1 += v; s2 += v * v;
            }
            #pragma unroll
            for (int mask = 1; mask < 16; mask <<= 1) {
                s1 += __shfl_xor(s1, mask);
                s2 += __shfl_xor(s2, mask);
            }
            if (l15 == 0) { sS1[wn][ml] = s1; sS2[wn][ml] = s2; }
        }
    }
    __syncthreads();
    if (tid < 128) {
        float s1 = sS1[0][tid] + sS1[1][tid] + sS1[2][tid] + sS1[3][tid];
        float s2 = sS2[0][tid] + sS2[1][tid] + sS2[2][tid] + sS2[3][tid];
        float mean = s1 * (1.f / 128.f);
        float var = s2 * (1.f / 128.f) - mean * mean;
        sMean[tid] = mean;
        sRstd[tid] = rsqrtf(var + 1e-5f);
    }
    __syncthreads();
    #pragma unroll
    for (int mt = 0; mt < 4; ++mt) {
        #pragma unroll
        for (int r = 0; r < 4; ++r) {
            int ml = wm * 64 + mt * 16 + quad * 4 + r;
            int node = node0 + ml;
            float mn = sMean[ml], rs = sRstd[ml];
            #pragma unroll
            for (int nt = 0; nt < 2; ++nt) {
                float v = (accm[mt][nt][r] - mn) * rs * pg[nt] + pbe[nt];
                if (OUT_BF16) {
                    float vh = __shfl_xor(v, 1);
                    if (!(l15 & 1)) {
                        // pad rows (node >= NNODES) written as zeros: they back
                        // ZROW reads in the next layer's gather.
                        uint val = (node < NNODES) ? pack2(v, vh) : 0u;
                        uint* o = (uint*)out;
                        o[(size_t)node * 64 + wn * 16 + nt * 8 + (l15 >> 1)] = val;
                    }
                } else {
                    if (node < NNODES) {
                        float* o = (float*)out;
                        o[(size_t)node * 128 + nl0 + nt * 16] = v;
                    }
                }
            }
        }
    }
}

// ---------------- launch ----------------

extern "C" void kernel_launch(void* const* d_in, const int* in_sizes, int n_in,
                              void* d_out, int out_size, void* d_ws, size_t ws_size,
                              hipStream_t stream) {
    (void)in_sizes; (void)n_in; (void)out_size; (void)ws_size;

    const int*   edges = (const int*)d_in[0];
    const float* xemb  = (const float*)d_in[1];
    const float* W1  = (const float*)d_in[2];
    const float* b1  = (const float*)d_in[3];
    const float* Ws1 = (const float*)d_in[4];
    const float* bs1 = (const float*)d_in[5];
    const float* g1  = (const float*)d_in[6];
    const float* be1 = (const float*)d_in[7];
    const float* W2  = (const float*)d_in[8];
    const float* b2  = (const float*)d_in[9];
    const float* Ws2 = (const float*)d_in[10];
    const float* bs2 = (const float*)d_in[11];
    const float* g2  = (const float*)d_in[12];
    const float* be2 = (const float*)d_in[13];

    char* ws = (char*)d_ws;
    auto take = [&](size_t bytes) {
        char* p = ws;
        ws += (bytes + 255) & ~(size_t)255;
        return p;
    };
    int*    elist  = (int*)take((size_t)NPAD * CAP * 4);
    uint*   segp   = (uint*)take((size_t)NPAD * 4);
    float4* cnts   = (float4*)take((size_t)NPAD * 16);
    uint*   xb0    = (uint*)take((size_t)NPAD * 128 * 2);
    uint*   xb1    = (uint*)take((size_t)NPAD * 128 * 2);
    uint*   Ab     = (uint*)take((size_t)NPAD * 384 * 2);
    uint*   Wb1    = (uint*)take((size_t)128 * 512 * 2);
    uint*   Wb2    = (uint*)take((size_t)128 * 512 * 2);
    int*    runcnt = (int*)take((size_t)NBLK_A * NBKT * 4);
    uint*   binned = (uint*)take((size_t)NBKT * NBLK_A * RUNCAP * 4);

    binfill_kernel<<<NBLK_A, 256, 0, stream>>>(edges, runcnt, binned);
    scatterx_kernel<<<NBKT + NCONVX + 256, 256, 0, stream>>>(
        binned, runcnt, elist, segp, cnts,
        xemb, xb0, W1, Ws1, Wb1, W2, Ws2, Wb2);

    gather_kernel<<<NNODES / 4, 256, 0, stream>>>(xb0, segp, elist, cnts, Ab);
    gemm_kernel<true><<<NPAD / 128, 512, 0, stream>>>(
        (const ushort*)Ab, (const ushort*)xb0, (const ushort*)Wb1,
        b1, bs1, g1, be1, cnts, xb1);

    gather_kernel<<<NNODES / 4, 256, 0, stream>>>(xb1, segp, elist, cnts, Ab);
    gemm_kernel<false><<<NPAD / 128, 512, 0, stream>>>(
        (const ushort*)Ab, (const ushort*)xb1, (const ushort*)Wb2,
        b2, bs2, g2, be2, cnts, d_out);
}